// Round 5
// baseline (4285.691 us; speedup 1.0000x reference)
//
#include <hip/hip_runtime.h>

#define EPS 0.01f
#define TSTEPS 2048
#define BATCH 64
// 2*log2(e): exp(2x) = exp2(x * TWOLOG2E). W and xu are pre-scaled by this
// at pack time so the tanh argument arrives ready for v_exp_f32 (exp2).
#define TWOLOG2E 2.8853900817779268f

typedef _Float16 half8 __attribute__((ext_vector_type(8)));
typedef _Float16 half4 __attribute__((ext_vector_type(4)));
typedef float f32x4 __attribute__((ext_vector_type(4)));
typedef unsigned long long u64;
typedef u64 u64x2 __attribute__((ext_vector_type(2)));

// ---------------------------------------------------------------------------
// prep_mc_pack: build Mc^T directly as f16 MFMA A-operand fragments.
// 16 unit-groups G (0..15), each 16 output cols 16G..16G+15.
// frag id f = (G*2 + mt)*8 + kk;  mt 0 = A-part (from B), mt 1 = W-part
// (from C, PRE-SCALED by TWOLOG2E so the scan's exp2 needs no extra mul).
// A-frag layout: lane l holds A[m=l&15][k=kk*32+(l>>4)*8+j], j=0..7, where
// A-operand element (c,k) = Mat[k][c], Mat = Src - 0.6*Src^T - 0.01I.
// ---------------------------------------------------------------------------
__global__ void prep_mc_pack(const float* __restrict__ Bm, const float* __restrict__ Cm,
                             _Float16* __restrict__ mcPack) {
    int f = blockIdx.x;       // 0..255
    int lane = threadIdx.x;   // 0..63
    int G = f >> 4;           // unit-group 0..15
    int mt = (f >> 3) & 1;    // 0=A, 1=W
    int kk = f & 7;
    const float* Src = (mt == 0) ? Bm : Cm;
    float scale = (mt == 0) ? 1.0f : TWOLOG2E;
    int c = 16 * G + (lane & 15);
    int k0 = kk * 32 + (lane >> 4) * 8;
    long off = ((long)f * 64 + lane) * 8;
#pragma unroll
    for (int j = 0; j < 8; ++j) {
        int k = k0 + j;
        float diag = (k == c) ? 0.01f : 0.0f;
        float v = scale * (Src[(long)k * 256 + c] - 0.6f * Src[(long)c * 256 + k] - diag);
        mcPack[off + j] = (_Float16)v;
    }
}

// ---------------------------------------------------------------------------
// pack_u: U (256x256 fp32) -> f16 B-operand fragments for xu_gemm.
// ---------------------------------------------------------------------------
__global__ void pack_u(const float* __restrict__ U, _Float16* __restrict__ up) {
    int t = blockIdx.x * 64 + threadIdx.x;
    int lane = t & 63;
    int tile = t >> 6;      // kk*16 + nn
    int nn = tile & 15;
    int kk = tile >> 4;
    int krow = kk * 32 + (lane >> 4) * 8;
    int col = nn * 16 + (lane & 15);
    long off = (long)t * 8;
#pragma unroll
    for (int jj = 0; jj < 8; ++jj) {
        up[off + jj] = (_Float16)U[(krow + jj) * 256 + col];
    }
}

// ---------------------------------------------------------------------------
// zero_sync: re-zero the cross-block staging buffers + flags each launch
// (stream-ordered before scan; makes graph replays / reruns safe and
// provides h0 = 0 for step 0's remote half).
// ---------------------------------------------------------------------------
__global__ void zero_sync(u64* __restrict__ stg, int* __restrict__ flags) {
    int t = blockIdx.x * 256 + threadIdx.x;   // 32 blocks x 256 = 8192
    stg[t] = 0ull;                            // 8 blocks x 2 parities x 512 u64 = 64 KB
    if (t < 128) flags[t] = 0;
}

// ---------------------------------------------------------------------------
// xu_gemm: out[r][n] = (sum_k x[r][k]*U[k][n] + bias[n]) * TWOLOG2E
// (pre-scaled tanh argument contribution). Writes into d_out; scan
// overwrites in place with h.
// ---------------------------------------------------------------------------
__global__ __launch_bounds__(256) void xu_gemm(const float* __restrict__ x,
                                               const _Float16* __restrict__ up,
                                               const float* __restrict__ bias,
                                               float* __restrict__ out) {
    int wave = threadIdx.x >> 6;
    int lane = threadIdx.x & 63;
    int m = lane & 15;
    int quad = lane >> 4;
    long row0 = (long)blockIdx.x * 64 + wave * 16;
    const float* xrow = x + (row0 + m) * 256 + quad * 8;

    f32x4 acc[16];
#pragma unroll
    for (int nn = 0; nn < 16; ++nn) acc[nn] = (f32x4){0.f, 0.f, 0.f, 0.f};

#pragma unroll
    for (int kk = 0; kk < 8; ++kk) {
        f32x4 xa = *(const f32x4*)(xrow + kk * 32);
        f32x4 xb = *(const f32x4*)(xrow + kk * 32 + 4);
        half8 af;
        af[0] = (_Float16)xa[0]; af[1] = (_Float16)xa[1];
        af[2] = (_Float16)xa[2]; af[3] = (_Float16)xa[3];
        af[4] = (_Float16)xb[0]; af[5] = (_Float16)xb[1];
        af[6] = (_Float16)xb[2]; af[7] = (_Float16)xb[3];
        const _Float16* ub = up + ((long)kk * 1024 + lane) * 8;
#pragma unroll
        for (int nn = 0; nn < 16; ++nn) {
            half8 bf = *(const half8*)(ub + (long)nn * 512);
            acc[nn] = __builtin_amdgcn_mfma_f32_16x16x32_f16(af, bf, acc[nn], 0, 0, 0);
        }
    }
#pragma unroll
    for (int nn = 0; nn < 16; ++nn) {
        int col = nn * 16 + m;
        float bv = bias[col];
#pragma unroll
        for (int i = 0; i < 4; ++i) {
            out[(row0 + quad * 4 + i) * 256 + col] = (acc[nn][i] + bv) * TWOLOG2E;
        }
    }
}

// ---------------------------------------------------------------------------
// scan_kernel: grid=8 (pairwise unit split -> 8 CUs, 2x the previous 4).
// Block b: batch group g=b>>1 (16 rows), unit half u=b&1 (units 128u..+127).
// 512 threads = 8 waves; wave w owns unit-group G=8u+w (16 cols, A+W chains,
// 16 MFMAs/step). Local h-half exchanged via LDS (double-buffered);
// partner's half via global staging written/read with AGENT-scope atomics
// (cross-XCD coherent), gated by a monotonic per-block flag:
//   step t: spin flag[b^1] >= t  ->  read staging[b^1][t&1]
//   ... compute ... write staging[b][(t+1)&1]; vmcnt(0); barrier;
//   tid0: flag[b] = t+1.
// Parity-2 staging is overwrite-safe: partner's reads of parity p complete
// before it sets flag=t, which we spin on before rewriting p.
// Remote loads are issued right after the spin and consumed after the
// 8 local-frag MFMAs, hiding the fabric latency. mcf is loaded LOCAL-FIRST
// (j=0..3 local kk, j=4..7 remote kk) so all register indexing is static.
// Elementwise: e=exp2(accW); r=rcp(e+1); hs'=accA+1-2r; h=EPS*hs'.
// ---------------------------------------------------------------------------
__global__ __launch_bounds__(512, 2) void scan_kernel(const _Float16* __restrict__ mcPack,
                                                      float* __restrict__ io,
                                                      u64* __restrict__ stg,
                                                      int* __restrict__ flags) {
    const int tid = threadIdx.x;
    const int w = tid >> 6;        // 0..7 (local wave)
    const int lane = tid & 63;
    const int m = lane & 15;
    const int q = lane >> 4;
    const int b = blockIdx.x;      // 0..7
    const int g = b >> 1;          // batch group 0..3
    const int u = b & 1;           // unit half
    const int G = 8 * u + w;       // global unit-group 0..15

    const int KL = 4 * u;          // local frag kk base
    const int KR = 4 - KL;         // remote frag kk base

    // Stationary A-operand fragments, LOCAL-FIRST order: j<4 -> kk=KL+j,
    // j>=4 -> kk=KR+j-4. All later indexing compile-time.
    half8 mcf[2][8];
#pragma unroll
    for (int mt = 0; mt < 2; ++mt)
#pragma unroll
        for (int j = 0; j < 8; ++j) {
            int kk = (j < 4) ? (KL + j) : (KR + j - 4);
            mcf[mt][j] = *(const half8*)(mcPack + (((long)(G * 2 + mt) * 8 + kk) * 64 + lane) * 8);
        }

    __shared__ _Float16 hB[2][2048];  // 2 x 4KB: local half of h as B-frags

    {   // zero buffer 0 (h0 = 0): 512 threads x 4 halfs
        half4 z = (half4)(_Float16)0.0f;
        *(half4*)(&hB[0][tid * 4]) = z;
    }

    const int rdIdx = lane * 8;
    // wave w's outputs -> local frag layout (local group w):
    const int wrIdx = 512 * (w >> 1) + 256 * (w & 1) + 128 * (q >> 1) + 8 * m + 4 * (q & 1);

    u64* const stgOwn0 = stg + ((long)b * 2 + 0) * 512;
    u64* const stgOwn1 = stg + ((long)b * 2 + 1) * 512;
    u64* const stgRem0 = stg + ((long)(b ^ 1) * 2 + 0) * 512;
    u64* const stgRem1 = stg + ((long)(b ^ 1) * 2 + 1) * 512;
    int* const flagOwn = flags + b * 16;         // 64B-spaced flags
    int* const flagRem = flags + (b ^ 1) * 16;

    // per-lane global pointer: row 16g+m, col 128u + 16w + 4q.
    float* p = io + ((long)(16 * g + m) * TSTEPS) * 256 + 128 * u + 16 * w + 4 * q;

    // hs = h/EPS for this lane's own output elements, starts 0.
    f32x4 hs = (f32x4){0.f, 0.f, 0.f, 0.f};

    f32x4 xq[2];
    xq[0] = *(const f32x4*)(p);
    xq[1] = *(const f32x4*)(p + 256);
    __syncthreads();

    auto step = [&](int t, const _Float16* hbR, _Float16* hbW,
                    u64* remIn, u64* ownOut, f32x4& xc) {
        // ---- wait for partner's staging for this step (t=0: passes) ----
        while (__hip_atomic_load(flagRem, __ATOMIC_RELAXED, __HIP_MEMORY_SCOPE_AGENT) < t) {}
        asm volatile("" ::: "memory");  // pin remote loads after the spin

        // ---- issue remote half loads early (consumed after local MFMAs) ----
        u64 rl0 = __hip_atomic_load(remIn + 0 * 128 + lane * 2,     __ATOMIC_RELAXED, __HIP_MEMORY_SCOPE_AGENT);
        u64 rh0 = __hip_atomic_load(remIn + 0 * 128 + lane * 2 + 1, __ATOMIC_RELAXED, __HIP_MEMORY_SCOPE_AGENT);
        u64 rl1 = __hip_atomic_load(remIn + 1 * 128 + lane * 2,     __ATOMIC_RELAXED, __HIP_MEMORY_SCOPE_AGENT);
        u64 rh1 = __hip_atomic_load(remIn + 1 * 128 + lane * 2 + 1, __ATOMIC_RELAXED, __HIP_MEMORY_SCOPE_AGENT);
        u64 rl2 = __hip_atomic_load(remIn + 2 * 128 + lane * 2,     __ATOMIC_RELAXED, __HIP_MEMORY_SCOPE_AGENT);
        u64 rh2 = __hip_atomic_load(remIn + 2 * 128 + lane * 2 + 1, __ATOMIC_RELAXED, __HIP_MEMORY_SCOPE_AGENT);
        u64 rl3 = __hip_atomic_load(remIn + 3 * 128 + lane * 2,     __ATOMIC_RELAXED, __HIP_MEMORY_SCOPE_AGENT);
        u64 rh3 = __hip_atomic_load(remIn + 3 * 128 + lane * 2 + 1, __ATOMIC_RELAXED, __HIP_MEMORY_SCOPE_AGENT);

        // ---- local half: LDS frags + chains (mcf j=0..3) ----
        half8 l0 = *(const half8*)(hbR + 0 * 512 + rdIdx);
        half8 l1 = *(const half8*)(hbR + 1 * 512 + rdIdx);
        half8 l2 = *(const half8*)(hbR + 2 * 512 + rdIdx);
        half8 l3 = *(const half8*)(hbR + 3 * 512 + rdIdx);

        f32x4 aA = __builtin_amdgcn_mfma_f32_16x16x32_f16(mcf[0][0], l0, hs, 0, 0, 0);
        f32x4 aW = __builtin_amdgcn_mfma_f32_16x16x32_f16(mcf[1][0], l0, xc, 0, 0, 0);
        aA = __builtin_amdgcn_mfma_f32_16x16x32_f16(mcf[0][1], l1, aA, 0, 0, 0);
        aW = __builtin_amdgcn_mfma_f32_16x16x32_f16(mcf[1][1], l1, aW, 0, 0, 0);
        aA = __builtin_amdgcn_mfma_f32_16x16x32_f16(mcf[0][2], l2, aA, 0, 0, 0);
        aW = __builtin_amdgcn_mfma_f32_16x16x32_f16(mcf[1][2], l2, aW, 0, 0, 0);
        aA = __builtin_amdgcn_mfma_f32_16x16x32_f16(mcf[0][3], l3, aA, 0, 0, 0);
        aW = __builtin_amdgcn_mfma_f32_16x16x32_f16(mcf[1][3], l3, aW, 0, 0, 0);

        // ---- remote half: chains (mcf j=4..7) ----
        half8 r0 = __builtin_bit_cast(half8, (u64x2){rl0, rh0});
        half8 r1 = __builtin_bit_cast(half8, (u64x2){rl1, rh1});
        half8 r2 = __builtin_bit_cast(half8, (u64x2){rl2, rh2});
        half8 r3 = __builtin_bit_cast(half8, (u64x2){rl3, rh3});

        aA = __builtin_amdgcn_mfma_f32_16x16x32_f16(mcf[0][4], r0, aA, 0, 0, 0);
        aW = __builtin_amdgcn_mfma_f32_16x16x32_f16(mcf[1][4], r0, aW, 0, 0, 0);
        aA = __builtin_amdgcn_mfma_f32_16x16x32_f16(mcf[0][5], r1, aA, 0, 0, 0);
        aW = __builtin_amdgcn_mfma_f32_16x16x32_f16(mcf[1][5], r1, aW, 0, 0, 0);
        aA = __builtin_amdgcn_mfma_f32_16x16x32_f16(mcf[0][6], r2, aA, 0, 0, 0);
        aW = __builtin_amdgcn_mfma_f32_16x16x32_f16(mcf[1][6], r2, aW, 0, 0, 0);
        aA = __builtin_amdgcn_mfma_f32_16x16x32_f16(mcf[0][7], r3, aA, 0, 0, 0);
        aW = __builtin_amdgcn_mfma_f32_16x16x32_f16(mcf[1][7], r3, aW, 0, 0, 0);

        // ---- elementwise (4 elems): hs' = accA + 1 - 2*rcp(exp2(accW)+1) ----
        f32x4 hn;
#pragma unroll
        for (int i = 0; i < 4; ++i) {
            float e = __builtin_amdgcn_exp2f(aW[i]);
            float r = __builtin_amdgcn_rcpf(e + 1.0f);
            float hsv = fmaf(-2.0f, r, aA[i] + 1.0f);
            hs[i] = hsv;
            hn[i] = EPS * hsv;
        }
        half4 h4;
#pragma unroll
        for (int i = 0; i < 4; ++i) h4[i] = (_Float16)hn[i];

        // ---- publish: LDS (local) + agent-scope staging (remote) ----
        *(half4*)(hbW + wrIdx) = h4;
        __hip_atomic_store(ownOut + (wrIdx >> 2), __builtin_bit_cast(u64, h4),
                           __ATOMIC_RELAXED, __HIP_MEMORY_SCOPE_AGENT);

        // drain staging store + LDS, then converge; flag after barrier.
        asm volatile("s_waitcnt vmcnt(0) lgkmcnt(0)\n\ts_barrier" ::: "memory");
        if (tid == 0)
            __hip_atomic_store(flagOwn, t + 1, __ATOMIC_RELAXED, __HIP_MEMORY_SCOPE_AGENT);

        // h_t -> global out (in place) + xu[t+2] prefetch, after the fence so
        // they never sit on the drain's critical path.
        *(f32x4*)(p) = hn;
        if (t + 2 < TSTEPS) {
            xc = *(const f32x4*)(p + 512);
        }
        p += 256;
    };

    for (int t = 0; t < TSTEPS; t += 2) {
        step(t,     hB[0], hB[1], stgRem0, stgOwn1, xq[0]);
        step(t + 1, hB[1], hB[0], stgRem1, stgOwn0, xq[1]);
    }
}

extern "C" void kernel_launch(void* const* d_in, const int* in_sizes, int n_in,
                              void* d_out, int out_size, void* d_ws, size_t ws_size,
                              hipStream_t stream) {
    const float* x    = (const float*)d_in[0];
    const float* C    = (const float*)d_in[1];
    const float* Bm   = (const float*)d_in[2];
    const float* U    = (const float*)d_in[3];
    const float* bias = (const float*)d_in[4];
    float* out = (float*)d_out;

    _Float16* mcPack = (_Float16*)d_ws;                           // 256 KB
    _Float16* up     = (_Float16*)((char*)d_ws + 262144);         // 128 KB
    u64*      stg    = (u64*)((char*)d_ws + 393216);              // 64 KB staging
    int*      flags  = (int*)((char*)d_ws + 458752);              // 512 B flags

    prep_mc_pack<<<256, 64, 0, stream>>>(Bm, C, mcPack);
    pack_u<<<128, 64, 0, stream>>>(U, up);
    zero_sync<<<32, 256, 0, stream>>>(stg, flags);
    xu_gemm<<<2048, 256, 0, stream>>>(x, up, bias, out);
    scan_kernel<<<8, 512, 0, stream>>>(mcPack, out, stg, flags);
}

// Round 6
// 2219.594 us; speedup vs baseline: 1.9308x; 1.9308x over previous
//
#include <hip/hip_runtime.h>

#define EPS 0.01f
#define TSTEPS 2048
#define BATCH 64
// 2*log2(e): exp(2x) = exp2(x * TWOLOG2E). W and xu are pre-scaled by this
// at pack time so the tanh argument arrives ready for v_exp_f32 (exp2).
#define TWOLOG2E 2.8853900817779268f

typedef _Float16 half8 __attribute__((ext_vector_type(8)));
typedef _Float16 half4 __attribute__((ext_vector_type(4)));
typedef float f32x4 __attribute__((ext_vector_type(4)));

// Workgroup barrier WITHOUT the vmcnt(0) drain the compiler emits for
// __syncthreads(). LDS visibility needs lgkmcnt(0) only; global loads
// (xu prefetch) and stores (h writeback) are lane-private and stay in
// flight across the barrier (AITER-style fine-grained pipelining).
#define LDS_BARRIER() asm volatile("s_waitcnt lgkmcnt(0)\n\ts_barrier" ::: "memory")

// ---------------------------------------------------------------------------
// prep_mc_pack: build Mc^T directly as f16 MFMA A-operand fragments.
// 16-wave decomposition: wave w (0..15) owns 16 output cols 16w..16w+15.
// frag id f = (w*2 + mt)*8 + kk;  mt 0 = A-part (from B), mt 1 = W-part
// (from C, PRE-SCALED by TWOLOG2E so the scan's exp2 needs no extra mul).
// A-frag layout: lane l holds A[m=l&15][k=kk*32+(l>>4)*8+j], j=0..7, where
// A-operand element (c,k) = Mat[k][c], Mat = Src - 0.6*Src^T - 0.01I.
// ---------------------------------------------------------------------------
__global__ void prep_mc_pack(const float* __restrict__ Bm, const float* __restrict__ Cm,
                             _Float16* __restrict__ mcPack) {
    int f = blockIdx.x;       // 0..255
    int lane = threadIdx.x;   // 0..63
    int w = f >> 4;           // wave 0..15
    int mt = (f >> 3) & 1;    // 0=A, 1=W
    int kk = f & 7;
    const float* Src = (mt == 0) ? Bm : Cm;
    float scale = (mt == 0) ? 1.0f : TWOLOG2E;
    int c = 16 * w + (lane & 15);
    int k0 = kk * 32 + (lane >> 4) * 8;
    long off = ((long)f * 64 + lane) * 8;
#pragma unroll
    for (int j = 0; j < 8; ++j) {
        int k = k0 + j;
        float diag = (k == c) ? 0.01f : 0.0f;
        float v = scale * (Src[(long)k * 256 + c] - 0.6f * Src[(long)c * 256 + k] - diag);
        mcPack[off + j] = (_Float16)v;
    }
}

// ---------------------------------------------------------------------------
// pack_u: U (256x256 fp32) -> f16 B-operand fragments for xu_gemm.
// ---------------------------------------------------------------------------
__global__ void pack_u(const float* __restrict__ U, _Float16* __restrict__ up) {
    int t = blockIdx.x * 64 + threadIdx.x;
    int lane = t & 63;
    int tile = t >> 6;      // kk*16 + nn
    int nn = tile & 15;
    int kk = tile >> 4;
    int krow = kk * 32 + (lane >> 4) * 8;
    int col = nn * 16 + (lane & 15);
    long off = (long)t * 8;
#pragma unroll
    for (int jj = 0; jj < 8; ++jj) {
        up[off + jj] = (_Float16)U[(krow + jj) * 256 + col];
    }
}

// ---------------------------------------------------------------------------
// xu_gemm: out[r][n] = (sum_k x[r][k]*U[k][n] + bias[n]) * TWOLOG2E
// (pre-scaled tanh argument contribution). Writes into d_out; scan
// overwrites in place with h.
// ---------------------------------------------------------------------------
__global__ __launch_bounds__(256) void xu_gemm(const float* __restrict__ x,
                                               const _Float16* __restrict__ up,
                                               const float* __restrict__ bias,
                                               float* __restrict__ out) {
    int wave = threadIdx.x >> 6;
    int lane = threadIdx.x & 63;
    int m = lane & 15;
    int quad = lane >> 4;
    long row0 = (long)blockIdx.x * 64 + wave * 16;
    const float* xrow = x + (row0 + m) * 256 + quad * 8;

    f32x4 acc[16];
#pragma unroll
    for (int nn = 0; nn < 16; ++nn) acc[nn] = (f32x4){0.f, 0.f, 0.f, 0.f};

#pragma unroll
    for (int kk = 0; kk < 8; ++kk) {
        f32x4 xa = *(const f32x4*)(xrow + kk * 32);
        f32x4 xb = *(const f32x4*)(xrow + kk * 32 + 4);
        half8 af;
        af[0] = (_Float16)xa[0]; af[1] = (_Float16)xa[1];
        af[2] = (_Float16)xa[2]; af[3] = (_Float16)xa[3];
        af[4] = (_Float16)xb[0]; af[5] = (_Float16)xb[1];
        af[6] = (_Float16)xb[2]; af[7] = (_Float16)xb[3];
        const _Float16* ub = up + ((long)kk * 1024 + lane) * 8;
#pragma unroll
        for (int nn = 0; nn < 16; ++nn) {
            half8 bf = *(const half8*)(ub + (long)nn * 512);
            acc[nn] = __builtin_amdgcn_mfma_f32_16x16x32_f16(af, bf, acc[nn], 0, 0, 0);
        }
    }
#pragma unroll
    for (int nn = 0; nn < 16; ++nn) {
        int col = nn * 16 + m;
        float bv = bias[col];
#pragma unroll
        for (int i = 0; i < 4; ++i) {
            out[(row0 + quad * 4 + i) * 256 + col] = (acc[nn][i] + bv) * TWOLOG2E;
        }
    }
}

// ---------------------------------------------------------------------------
// scan_kernel: grid=4 (16 batch rows each), 1024 threads = 16 waves,
// 4 waves/SIMD. Wave w owns 16 output cols (1 A-tile + 1 W-tile = 16
// MFMAs/step); Mc fragments stationary (64 regs -> AGPRs); h double-buffered
// in LDS as f16 B-frags; xu read in-place from d_out (2-step prefetch,
// pre-scaled by TWOLOG2E) and overwritten with h_t.
//
// Round-6 (isolating R4's variables; setprio REMOVED — m190: it hurts
// barrier-lockstep structures):
//  * Chain split: phase-2 MFMAs (kk=4..7) accumulate into FRESH accumulators
//    -> two 4-deep chains instead of one 8-deep; phase 2 starts as soon as
//    hb4 lands. Combined in EW.
//  * The tanh "+1" is folded into phase-2 A-chain's C-init (C = 1.0), so the
//    combine aA0+aA1 carries it for free.
// Elementwise: e=exp2(sW); r=rcp(e+1); hs'=sA-2r (sA includes +1); h=EPS*hs'.
// ---------------------------------------------------------------------------
__global__ __launch_bounds__(1024, 4) void scan_kernel(const _Float16* __restrict__ mcPack,
                                                       float* __restrict__ io) {
    const int tid = threadIdx.x;
    const int w = tid >> 6;       // 0..15
    const int lane = tid & 63;
    const int m = lane & 15;
    const int q = lane >> 4;
    const int b0 = blockIdx.x * 16;

    // Stationary A-operand fragments: 2 M-tiles (A,W) x 8 K-steps = 64 regs.
    half8 mcf[2][8];
#pragma unroll
    for (int mt = 0; mt < 2; ++mt)
#pragma unroll
        for (int kk = 0; kk < 8; ++kk)
            mcf[mt][kk] = *(const half8*)(mcPack + (((long)(w * 2 + mt) * 8 + kk) * 64 + lane) * 8);

    __shared__ _Float16 hB[2][4096];  // 2 x 8KB double buffer, h^T as B-frags

    // zero buffer 0 (h0 = 0): 1024 threads x 4 halfs
    {
        half4 z = (half4)(_Float16)0.0f;
        *(half4*)(&hB[0][tid * 4]) = z;
    }

    const int rdIdx = lane * 8;
    // wave w's 16 units live in frag kk'=w>>1, k_local base 16*(w&1):
    // element (batch m, unit 16w+4q+i) -> half index
    //   512*(w>>1) + 256*(w&1) + 128*(q>>1) + 8*m + 4*(q&1) + i
    const int wrIdx = 512 * (w >> 1) + 256 * (w & 1) + 128 * (q >> 1) + 8 * m + 4 * (q & 1);

    // per-lane global pointer: row b0+m, col 16w+4q.
    float* p = io + ((long)(b0 + m) * TSTEPS) * 256 + 16 * w + 4 * q;

    // hs = h/EPS for this lane's own output elements (acc layout), starts 0.
    f32x4 hs = (f32x4){0.f, 0.f, 0.f, 0.f};

    f32x4 xq[2];
    xq[0] = *(const f32x4*)(p);
    xq[1] = *(const f32x4*)(p + 256);
    __syncthreads();

    const f32x4 zf  = (f32x4){0.f, 0.f, 0.f, 0.f};
    const f32x4 onef = (f32x4){1.f, 1.f, 1.f, 1.f};

    auto step = [&](int t, const _Float16* hbR, _Float16* hbW, f32x4& xc) {
        // ---- phase 1: read h frags 0..3, chains A0/W0 (C-init hs / xu) ----
        half8 hb0 = *(const half8*)(hbR + 0 * 512 + rdIdx);
        half8 hb1 = *(const half8*)(hbR + 1 * 512 + rdIdx);
        half8 hb2 = *(const half8*)(hbR + 2 * 512 + rdIdx);
        half8 hb3 = *(const half8*)(hbR + 3 * 512 + rdIdx);

        f32x4 aA0 = __builtin_amdgcn_mfma_f32_16x16x32_f16(mcf[0][0], hb0, hs, 0, 0, 0);
        f32x4 aW0 = __builtin_amdgcn_mfma_f32_16x16x32_f16(mcf[1][0], hb0, xc, 0, 0, 0);
        aA0 = __builtin_amdgcn_mfma_f32_16x16x32_f16(mcf[0][1], hb1, aA0, 0, 0, 0);
        aW0 = __builtin_amdgcn_mfma_f32_16x16x32_f16(mcf[1][1], hb1, aW0, 0, 0, 0);
        aA0 = __builtin_amdgcn_mfma_f32_16x16x32_f16(mcf[0][2], hb2, aA0, 0, 0, 0);
        aW0 = __builtin_amdgcn_mfma_f32_16x16x32_f16(mcf[1][2], hb2, aW0, 0, 0, 0);
        aA0 = __builtin_amdgcn_mfma_f32_16x16x32_f16(mcf[0][3], hb3, aA0, 0, 0, 0);
        aW0 = __builtin_amdgcn_mfma_f32_16x16x32_f16(mcf[1][3], hb3, aW0, 0, 0, 0);

        // ---- phase 2: read h frags 4..7, FRESH chains A1 (C=1.0) / W1 ----
        half8 hb4 = *(const half8*)(hbR + 4 * 512 + rdIdx);
        half8 hb5 = *(const half8*)(hbR + 5 * 512 + rdIdx);
        half8 hb6 = *(const half8*)(hbR + 6 * 512 + rdIdx);
        half8 hb7 = *(const half8*)(hbR + 7 * 512 + rdIdx);

        f32x4 aA1 = __builtin_amdgcn_mfma_f32_16x16x32_f16(mcf[0][4], hb4, onef, 0, 0, 0);
        f32x4 aW1 = __builtin_amdgcn_mfma_f32_16x16x32_f16(mcf[1][4], hb4, zf, 0, 0, 0);
        aA1 = __builtin_amdgcn_mfma_f32_16x16x32_f16(mcf[0][5], hb5, aA1, 0, 0, 0);
        aW1 = __builtin_amdgcn_mfma_f32_16x16x32_f16(mcf[1][5], hb5, aW1, 0, 0, 0);
        aA1 = __builtin_amdgcn_mfma_f32_16x16x32_f16(mcf[0][6], hb6, aA1, 0, 0, 0);
        aW1 = __builtin_amdgcn_mfma_f32_16x16x32_f16(mcf[1][6], hb6, aW1, 0, 0, 0);
        aA1 = __builtin_amdgcn_mfma_f32_16x16x32_f16(mcf[0][7], hb7, aA1, 0, 0, 0);
        aW1 = __builtin_amdgcn_mfma_f32_16x16x32_f16(mcf[1][7], hb7, aW1, 0, 0, 0);

        // ---- elementwise (4 elems): combine partials, tanh, update ----
        f32x4 hn;
#pragma unroll
        for (int i = 0; i < 4; ++i) {
            float sW = aW0[i] + aW1[i];
            float e = __builtin_amdgcn_exp2f(sW);
            float r = __builtin_amdgcn_rcpf(e + 1.0f);
            float sA = aA0[i] + aA1[i];          // includes the +1 via C-init
            float hsv = fmaf(-2.0f, r, sA);
            hs[i] = hsv;
            hn[i] = EPS * hsv;
        }
        half4 h4;
#pragma unroll
        for (int i = 0; i < 4; ++i) h4[i] = (_Float16)hn[i];
        *(half4*)(hbW + wrIdx) = h4;   // next-step B-frags (LDS)
        *(f32x4*)(p) = hn;             // h_t -> global out (in place)

        // ---- prefetch xu[t+2] (stays in flight across the barrier) ----
        if (t + 2 < TSTEPS) {
            xc = *(const f32x4*)(p + 512);
        }
        p += 256;
        LDS_BARRIER();  // lgkmcnt(0)-only barrier: no vmcnt drain
    };

    for (int t = 0; t < TSTEPS; t += 2) {
        step(t, hB[0], hB[1], xq[0]);
        step(t + 1, hB[1], hB[0], xq[1]);
    }
}

extern "C" void kernel_launch(void* const* d_in, const int* in_sizes, int n_in,
                              void* d_out, int out_size, void* d_ws, size_t ws_size,
                              hipStream_t stream) {
    const float* x    = (const float*)d_in[0];
    const float* C    = (const float*)d_in[1];
    const float* Bm   = (const float*)d_in[2];
    const float* U    = (const float*)d_in[3];
    const float* bias = (const float*)d_in[4];
    float* out = (float*)d_out;

    _Float16* mcPack = (_Float16*)d_ws;                         // 256 KB
    _Float16* up     = (_Float16*)((char*)d_ws + 262144);       // 128 KB

    prep_mc_pack<<<256, 64, 0, stream>>>(Bm, C, mcPack);
    pack_u<<<128, 64, 0, stream>>>(U, up);
    xu_gemm<<<2048, 256, 0, stream>>>(x, up, bias, out);
    scan_kernel<<<4, 1024, 0, stream>>>(mcPack, out);
}

// Round 7
// 2019.626 us; speedup vs baseline: 2.1220x; 1.0990x over previous
//
#include <hip/hip_runtime.h>

#define EPS 0.01f
#define TSTEPS 2048
#define BATCH 64
// 2*log2(e): exp(2x) = exp2(x * TWOLOG2E). W and xu are pre-scaled by this
// at pack time so the tanh argument arrives ready for v_exp_f32 (exp2).
#define TWOLOG2E 2.8853900817779268f

typedef _Float16 half8 __attribute__((ext_vector_type(8)));
typedef _Float16 half4 __attribute__((ext_vector_type(4)));
typedef float f32x4 __attribute__((ext_vector_type(4)));

// Workgroup barrier WITHOUT the vmcnt(0) drain the compiler emits for
// __syncthreads(). LDS visibility needs lgkmcnt(0) only; global loads
// (xu prefetch) and stores (h writeback) are lane-private and stay in
// flight across the barrier (AITER-style fine-grained pipelining).
#define LDS_BARRIER() asm volatile("s_waitcnt lgkmcnt(0)\n\ts_barrier" ::: "memory")

// ---------------------------------------------------------------------------
// prep_mc_pack: build Mc^T directly as f16 MFMA A-operand fragments.
// 16 unit-groups: wave w (0..15) owns 16 output cols 16w..16w+15.
// frag id f = (w*2 + mt)*8 + kk;  mt 0 = A-part (from B), mt 1 = W-part
// (from C, PRE-SCALED by TWOLOG2E so the scan's exp2 needs no extra mul).
// A-frag layout: lane l holds A[m=l&15][k=kk*32+(l>>4)*8+j], j=0..7, where
// A-operand element (c,k) = Mat[k][c], Mat = Src - 0.6*Src^T - 0.01I.
// ---------------------------------------------------------------------------
__global__ void prep_mc_pack(const float* __restrict__ Bm, const float* __restrict__ Cm,
                             _Float16* __restrict__ mcPack) {
    int f = blockIdx.x;       // 0..255
    int lane = threadIdx.x;   // 0..63
    int w = f >> 4;           // wave 0..15
    int mt = (f >> 3) & 1;    // 0=A, 1=W
    int kk = f & 7;
    const float* Src = (mt == 0) ? Bm : Cm;
    float scale = (mt == 0) ? 1.0f : TWOLOG2E;
    int c = 16 * w + (lane & 15);
    int k0 = kk * 32 + (lane >> 4) * 8;
    long off = ((long)f * 64 + lane) * 8;
#pragma unroll
    for (int j = 0; j < 8; ++j) {
        int k = k0 + j;
        float diag = (k == c) ? 0.01f : 0.0f;
        float v = scale * (Src[(long)k * 256 + c] - 0.6f * Src[(long)c * 256 + k] - diag);
        mcPack[off + j] = (_Float16)v;
    }
}

// ---------------------------------------------------------------------------
// pack_u: U (256x256 fp32) -> f16 B-operand fragments for xu_gemm.
// ---------------------------------------------------------------------------
__global__ void pack_u(const float* __restrict__ U, _Float16* __restrict__ up) {
    int t = blockIdx.x * 64 + threadIdx.x;
    int lane = t & 63;
    int tile = t >> 6;      // kk*16 + nn
    int nn = tile & 15;
    int kk = tile >> 4;
    int krow = kk * 32 + (lane >> 4) * 8;
    int col = nn * 16 + (lane & 15);
    long off = (long)t * 8;
#pragma unroll
    for (int jj = 0; jj < 8; ++jj) {
        up[off + jj] = (_Float16)U[(krow + jj) * 256 + col];
    }
}

// ---------------------------------------------------------------------------
// xu_gemm: out[r][n] = (sum_k x[r][k]*U[k][n] + bias[n]) * TWOLOG2E
// (pre-scaled tanh argument contribution). Writes into d_out; scan
// overwrites in place with h.
// ---------------------------------------------------------------------------
__global__ __launch_bounds__(256) void xu_gemm(const float* __restrict__ x,
                                               const _Float16* __restrict__ up,
                                               const float* __restrict__ bias,
                                               float* __restrict__ out) {
    int wave = threadIdx.x >> 6;
    int lane = threadIdx.x & 63;
    int m = lane & 15;
    int quad = lane >> 4;
    long row0 = (long)blockIdx.x * 64 + wave * 16;
    const float* xrow = x + (row0 + m) * 256 + quad * 8;

    f32x4 acc[16];
#pragma unroll
    for (int nn = 0; nn < 16; ++nn) acc[nn] = (f32x4){0.f, 0.f, 0.f, 0.f};

#pragma unroll
    for (int kk = 0; kk < 8; ++kk) {
        f32x4 xa = *(const f32x4*)(xrow + kk * 32);
        f32x4 xb = *(const f32x4*)(xrow + kk * 32 + 4);
        half8 af;
        af[0] = (_Float16)xa[0]; af[1] = (_Float16)xa[1];
        af[2] = (_Float16)xa[2]; af[3] = (_Float16)xa[3];
        af[4] = (_Float16)xb[0]; af[5] = (_Float16)xb[1];
        af[6] = (_Float16)xb[2]; af[7] = (_Float16)xb[3];
        const _Float16* ub = up + ((long)kk * 1024 + lane) * 8;
#pragma unroll
        for (int nn = 0; nn < 16; ++nn) {
            half8 bf = *(const half8*)(ub + (long)nn * 512);
            acc[nn] = __builtin_amdgcn_mfma_f32_16x16x32_f16(af, bf, acc[nn], 0, 0, 0);
        }
    }
#pragma unroll
    for (int nn = 0; nn < 16; ++nn) {
        int col = nn * 16 + m;
        float bv = bias[col];
#pragma unroll
        for (int i = 0; i < 4; ++i) {
            out[(row0 + quad * 4 + i) * 256 + col] = (acc[nn][i] + bv) * TWOLOG2E;
        }
    }
}

// ---------------------------------------------------------------------------
// scan_kernel: grid=8 (8 batch rows each -> 8 CUs), 1024 threads = 16 waves,
// 4 waves/SIMD. Per-CU MFMA work (256 MFMAs/step) is batch-independent, so
// the batch split doubles CUs at constant per-CU MFMA; the win is that the
// LDS h-tile halves (8 real rows), dropping the LDS pipe below the MFMA pipe.
//
// Pad handling (MFMA N=16, only 8 real batch rows):
//  * B-frag pad-column zeros come from REGISTERS, not LDS: the pad-reader
//    lanes are exactly (lane&8)!=0, and rdIdx = (lane & ~8)*8 makes each pad
//    lane read its partner's address -> same-address pair BROADCASTS in the
//    LDS crossbar (no conflict) -> bank traffic halves (~half read cycles).
//    Pad lanes' B values are then real data feeding only never-read pad D
//    columns (garbage, harmless).
//  * LDS h-writes are unmasked (pad region of the buffer is never read).
//  * Global xu loads / h stores are masked to m<8 (other rows belong to
//    other blocks -> must not touch).
// Keeps R6's chain split (two 4-deep chains, fresh accumulators, tanh +1
// folded into phase-2 A-chain C-init) and the lgkmcnt-only barrier.
// Elementwise: e=exp2(sW); r=rcp(e+1); hs'=sA-2r (sA includes +1); h=EPS*hs'.
// ---------------------------------------------------------------------------
__global__ __launch_bounds__(1024, 4) void scan_kernel(const _Float16* __restrict__ mcPack,
                                                       float* __restrict__ io) {
    const int tid = threadIdx.x;
    const int w = tid >> 6;       // 0..15
    const int lane = tid & 63;
    const int m = lane & 15;
    const int q = lane >> 4;
    const int b0 = blockIdx.x * 8;      // 8 batch rows per block
    const bool act = (m < 8);           // lanes owning real batch rows

    // Stationary A-operand fragments: 2 M-tiles (A,W) x 8 K-steps = 64 regs.
    half8 mcf[2][8];
#pragma unroll
    for (int mt = 0; mt < 2; ++mt)
#pragma unroll
        for (int kk = 0; kk < 8; ++kk)
            mcf[mt][kk] = *(const half8*)(mcPack + (((long)(w * 2 + mt) * 8 + kk) * 64 + lane) * 8);

    __shared__ _Float16 hB[2][4096];  // 2 x 8KB double buffer, h^T as B-frags

    // zero BOTH buffers (h0 = 0 for real rows; pad region defined too)
    {
        half8 z = (half8)(_Float16)0.0f;
        *(half8*)(((_Float16*)hB) + (long)tid * 8) = z;   // 1024 x 16B = 16KB
    }

    // broadcast-read index: pad lanes (lane&8) read their partner's address;
    // same-address pairs broadcast -> half LDS bank traffic.
    const int rdIdx = (lane & ~8) * 8;
    // wave w's 16 units live in frag kk'=w>>1, k_local base 16*(w&1):
    // element (batch m, unit 16w+4q+i) -> half index
    //   512*(w>>1) + 256*(w&1) + 128*(q>>1) + 8*m + 4*(q&1) + i
    const int wrIdx = 512 * (w >> 1) + 256 * (w & 1) + 128 * (q >> 1) + 8 * m + 4 * (q & 1);

    // per-lane global pointer: row b0+m (valid only for m<8), col 16w+4q.
    float* p = io + ((long)(b0 + m) * TSTEPS) * 256 + 16 * w + 4 * q;

    // hs = h/EPS for this lane's own output elements (acc layout), starts 0.
    f32x4 hs = (f32x4){0.f, 0.f, 0.f, 0.f};

    const f32x4 zf   = (f32x4){0.f, 0.f, 0.f, 0.f};
    const f32x4 onef = (f32x4){1.f, 1.f, 1.f, 1.f};

    f32x4 xq[2] = {zf, zf};
    if (act) {
        xq[0] = *(const f32x4*)(p);
        xq[1] = *(const f32x4*)(p + 256);
    }
    __syncthreads();

    auto step = [&](int t, const _Float16* hbR, _Float16* hbW, f32x4& xc) {
        // ---- phase 1: read h frags 0..3, chains A0/W0 (C-init hs / xu) ----
        half8 hb0 = *(const half8*)(hbR + 0 * 512 + rdIdx);
        half8 hb1 = *(const half8*)(hbR + 1 * 512 + rdIdx);
        half8 hb2 = *(const half8*)(hbR + 2 * 512 + rdIdx);
        half8 hb3 = *(const half8*)(hbR + 3 * 512 + rdIdx);

        f32x4 aA0 = __builtin_amdgcn_mfma_f32_16x16x32_f16(mcf[0][0], hb0, hs, 0, 0, 0);
        f32x4 aW0 = __builtin_amdgcn_mfma_f32_16x16x32_f16(mcf[1][0], hb0, xc, 0, 0, 0);
        aA0 = __builtin_amdgcn_mfma_f32_16x16x32_f16(mcf[0][1], hb1, aA0, 0, 0, 0);
        aW0 = __builtin_amdgcn_mfma_f32_16x16x32_f16(mcf[1][1], hb1, aW0, 0, 0, 0);
        aA0 = __builtin_amdgcn_mfma_f32_16x16x32_f16(mcf[0][2], hb2, aA0, 0, 0, 0);
        aW0 = __builtin_amdgcn_mfma_f32_16x16x32_f16(mcf[1][2], hb2, aW0, 0, 0, 0);
        aA0 = __builtin_amdgcn_mfma_f32_16x16x32_f16(mcf[0][3], hb3, aA0, 0, 0, 0);
        aW0 = __builtin_amdgcn_mfma_f32_16x16x32_f16(mcf[1][3], hb3, aW0, 0, 0, 0);

        // ---- phase 2: read h frags 4..7, FRESH chains A1 (C=1.0) / W1 ----
        half8 hb4 = *(const half8*)(hbR + 4 * 512 + rdIdx);
        half8 hb5 = *(const half8*)(hbR + 5 * 512 + rdIdx);
        half8 hb6 = *(const half8*)(hbR + 6 * 512 + rdIdx);
        half8 hb7 = *(const half8*)(hbR + 7 * 512 + rdIdx);

        f32x4 aA1 = __builtin_amdgcn_mfma_f32_16x16x32_f16(mcf[0][4], hb4, onef, 0, 0, 0);
        f32x4 aW1 = __builtin_amdgcn_mfma_f32_16x16x32_f16(mcf[1][4], hb4, zf, 0, 0, 0);
        aA1 = __builtin_amdgcn_mfma_f32_16x16x32_f16(mcf[0][5], hb5, aA1, 0, 0, 0);
        aW1 = __builtin_amdgcn_mfma_f32_16x16x32_f16(mcf[1][5], hb5, aW1, 0, 0, 0);
        aA1 = __builtin_amdgcn_mfma_f32_16x16x32_f16(mcf[0][6], hb6, aA1, 0, 0, 0);
        aW1 = __builtin_amdgcn_mfma_f32_16x16x32_f16(mcf[1][6], hb6, aW1, 0, 0, 0);
        aA1 = __builtin_amdgcn_mfma_f32_16x16x32_f16(mcf[0][7], hb7, aA1, 0, 0, 0);
        aW1 = __builtin_amdgcn_mfma_f32_16x16x32_f16(mcf[1][7], hb7, aW1, 0, 0, 0);

        // ---- elementwise (4 elems): combine partials, tanh, update ----
        f32x4 hn;
#pragma unroll
        for (int i = 0; i < 4; ++i) {
            float sW = aW0[i] + aW1[i];
            float e = __builtin_amdgcn_exp2f(sW);
            float r = __builtin_amdgcn_rcpf(e + 1.0f);
            float sA = aA0[i] + aA1[i];          // includes the +1 via C-init
            float hsv = fmaf(-2.0f, r, sA);
            hs[i] = hsv;
            hn[i] = EPS * hsv;
        }
        half4 h4;
#pragma unroll
        for (int i = 0; i < 4; ++i) h4[i] = (_Float16)hn[i];
        *(half4*)(hbW + wrIdx) = h4;   // next-step B-frags (pad region never read)

        // global I/O masked to real rows (other rows belong to other blocks)
        if (act) {
            *(f32x4*)(p) = hn;                       // h_t -> global out (in place)
            if (t + 2 < TSTEPS) {
                xc = *(const f32x4*)(p + 512);       // prefetch xu[t+2]
            }
        }
        p += 256;
        LDS_BARRIER();  // lgkmcnt(0)-only barrier: no vmcnt drain
    };

    for (int t = 0; t < TSTEPS; t += 2) {
        step(t, hB[0], hB[1], xq[0]);
        step(t + 1, hB[1], hB[0], xq[1]);
    }
}

extern "C" void kernel_launch(void* const* d_in, const int* in_sizes, int n_in,
                              void* d_out, int out_size, void* d_ws, size_t ws_size,
                              hipStream_t stream) {
    const float* x    = (const float*)d_in[0];
    const float* C    = (const float*)d_in[1];
    const float* Bm   = (const float*)d_in[2];
    const float* U    = (const float*)d_in[3];
    const float* bias = (const float*)d_in[4];
    float* out = (float*)d_out;

    _Float16* mcPack = (_Float16*)d_ws;                         // 256 KB
    _Float16* up     = (_Float16*)((char*)d_ws + 262144);       // 128 KB

    prep_mc_pack<<<256, 64, 0, stream>>>(Bm, C, mcPack);
    pack_u<<<128, 64, 0, stream>>>(U, up);
    xu_gemm<<<2048, 256, 0, stream>>>(x, up, bias, out);
    scan_kernel<<<8, 1024, 0, stream>>>(mcPack, out);
}